// Round 1
// baseline (78151.471 us; speedup 1.0000x reference)
//
#include <hip/hip_runtime.h>
#include <stdint.h>
#include <stddef.h>

typedef _Float16 h2 __attribute__((ext_vector_type(2)));

#define T_STEPS 32768
#define HDIM    256

__device__ __forceinline__ float sigmoidf_(float x) {
    return 1.0f / (1.0f + __expf(-x));
}
__device__ __forceinline__ float tanhf_(float x) {
    // tanh(x) = 1 - 2/(exp(2x)+1); safe at +/-inf of exp
    float e2 = __expf(2.0f * x);
    return 1.0f - 2.0f / (e2 + 1.0f);
}

// One block, 256 threads = 4 waves (1 wave/SIMD). Thread i owns GRU rows
// {i, 256+i, 512+i} so the gate elementwise needs no cross-thread traffic.
// Weights live in VGPRs as packed f16 pairs (384 regs); h is broadcast via a
// 512B double-buffered LDS array of f16. One __syncthreads per event step.
__global__ __launch_bounds__(256, 1)
void aether_gru_kernel(const float* __restrict__ xg,
                       const float* __restrict__ wih,
                       const float* __restrict__ whh,
                       const float* __restrict__ bih,
                       const float* __restrict__ bhh,
                       const float* __restrict__ wfc,
                       const float* __restrict__ bfc,
                       float* __restrict__ out) {
    const int tid  = threadIdx.x;
    const int lane = tid & 63;
    const int wid  = tid >> 6;

    __shared__ __align__(16) _Float16 hbuf[2][HDIM];
    __shared__ float pp[2][4];

    // ---- load per-thread weights into registers (f16 pairs) ----
    h2 wr[128], wz[128], wn[128];
    {
        const float2* p = (const float2*)(whh + (size_t)tid * HDIM);
        #pragma unroll
        for (int k = 0; k < 128; ++k) {
            float2 w = p[k];
            h2 v; v.x = (_Float16)w.x; v.y = (_Float16)w.y; wr[k] = v;
        }
    }
    {
        const float2* p = (const float2*)(whh + (size_t)(HDIM + tid) * HDIM);
        #pragma unroll
        for (int k = 0; k < 128; ++k) {
            float2 w = p[k];
            h2 v; v.x = (_Float16)w.x; v.y = (_Float16)w.y; wz[k] = v;
        }
    }
    {
        const float2* p = (const float2*)(whh + (size_t)(2 * HDIM + tid) * HDIM);
        #pragma unroll
        for (int k = 0; k < 128; ++k) {
            float2 w = p[k];
            h2 v; v.x = (_Float16)w.x; v.y = (_Float16)w.y; wn[k] = v;
        }
    }

    // per-thread scalar constants
    const float wxr = wih[2 * tid],              wdr = wih[2 * tid + 1];
    const float wxz = wih[2 * (HDIM + tid)],     wdz = wih[2 * (HDIM + tid) + 1];
    const float wxn = wih[2 * (2 * HDIM + tid)], wdn = wih[2 * (2 * HDIM + tid) + 1];
    const float br = bih[tid], bz = bih[HDIM + tid], bn = bih[2 * HDIM + tid];
    const float cr = bhh[tid], cz = bhh[HDIM + tid], cn = bhh[2 * HDIM + tid];
    const float wf = wfc[tid];
    const float bf = bfc[0];

    hbuf[0][tid] = (_Float16)0.0f;
    __syncthreads();

    // sequential state (identical in every thread -> uniform branches)
    float h        = 0.0f;
    float last_val = xg[0] + 1.24f;   // xs[0] + (2*THRESHOLD + 1.0)
    float last_t   = 0.0f;
    int   cnt      = 0;
    int   cur      = 0;   // hbuf read index
    int   pe       = 0;   // pp parity
    float cur_pred = 0.0f;

    float xc = xg[0];
    float xn = xg[1];

    float* recon = out;
    float* idxp  = out + T_STEPS + 1;

    for (int t = 0; t < T_STEPS; ++t) {
        int t2 = t + 2; if (t2 > T_STEPS - 1) t2 = T_STEPS - 1;
        float xf = xg[t2];                       // prefetch (broadcast load)
        const float tf = (float)t;
        const bool ev = fabsf(xc - last_val) >= 0.12f;

        if (ev) {
            const float dtv = (tf - last_t) / 100.0f;
            const float gir = fmaf(wxr, xc, fmaf(wdr, dtv, br));
            const float giz = fmaf(wxz, xc, fmaf(wdz, dtv, bz));
            const float gin = fmaf(wxn, xc, fmaf(wdn, dtv, bn));

            float ar = cr, az = cz, an = cn;     // fold b_hh into accumulators
            const uint4* hb = (const uint4*)(&hbuf[cur][0]);
            #pragma unroll
            for (int c = 0; c < 32; ++c) {
                uint4 q = hb[c];                 // 8 f16 = 4 pairs, LDS broadcast
                h2 p0 = __builtin_bit_cast(h2, q.x);
                h2 p1 = __builtin_bit_cast(h2, q.y);
                h2 p2 = __builtin_bit_cast(h2, q.z);
                h2 p3 = __builtin_bit_cast(h2, q.w);
                const int k = c * 4;
                ar = __builtin_amdgcn_fdot2(wr[k + 0], p0, ar, false);
                az = __builtin_amdgcn_fdot2(wz[k + 0], p0, az, false);
                an = __builtin_amdgcn_fdot2(wn[k + 0], p0, an, false);
                ar = __builtin_amdgcn_fdot2(wr[k + 1], p1, ar, false);
                az = __builtin_amdgcn_fdot2(wz[k + 1], p1, az, false);
                an = __builtin_amdgcn_fdot2(wn[k + 1], p1, an, false);
                ar = __builtin_amdgcn_fdot2(wr[k + 2], p2, ar, false);
                az = __builtin_amdgcn_fdot2(wz[k + 2], p2, az, false);
                an = __builtin_amdgcn_fdot2(wn[k + 2], p2, an, false);
                ar = __builtin_amdgcn_fdot2(wr[k + 3], p3, ar, false);
                az = __builtin_amdgcn_fdot2(wz[k + 3], p3, az, false);
                an = __builtin_amdgcn_fdot2(wn[k + 3], p3, an, false);
            }

            const float r = sigmoidf_(gir + ar);
            const float z = sigmoidf_(giz + az);
            const float n = tanhf_(fmaf(r, an, gin));
            h = fmaf(z, h, (1.0f - z) * n);      // (1-z)*n + z*h

            hbuf[cur ^ 1][tid] = (_Float16)h;

            // fc projection partial: wave shfl-reduce, one slot per wave
            float pv = h * wf;
            pv += __shfl_down(pv, 32);
            pv += __shfl_down(pv, 16);
            pv += __shfl_down(pv, 8);
            pv += __shfl_down(pv, 4);
            pv += __shfl_down(pv, 2);
            pv += __shfl_down(pv, 1);
            if (lane == 0) pp[pe][wid] = pv;
            if (tid == 0) idxp[cnt] = tf;        // ascending -> already sorted

            last_val = xc;
            last_t   = tf;
            cnt++;

            __syncthreads();                      // publish hbuf + pp
            cur ^= 1;
            if (tid == 0)
                cur_pred = pp[pe][0] + pp[pe][1] + pp[pe][2] + pp[pe][3] + bf;
            pe ^= 1;
        }

        if (tid == 0) recon[t] = cur_pred;        // pred constant between events
        xc = xn; xn = xf;
    }

    if (tid == 0) out[T_STEPS] = (float)cnt;      // n_events
    for (int j = cnt + tid; j < T_STEPS; j += 256)
        idxp[j] = 32768.0f;                       // pad with T
}

__global__ void aether_dummy_unused() {}

extern "C" void kernel_launch(void* const* d_in, const int* in_sizes, int n_in,
                              void* d_out, int out_size, void* d_ws, size_t ws_size,
                              hipStream_t stream) {
    const float* x    = (const float*)d_in[0];
    const float* wih  = (const float*)d_in[1];
    const float* whh  = (const float*)d_in[2];
    const float* bih  = (const float*)d_in[3];
    const float* bhh  = (const float*)d_in[4];
    const float* wfc  = (const float*)d_in[5];
    const float* bfc  = (const float*)d_in[6];
    float* out = (float*)d_out;

    hipLaunchKernelGGL(aether_gru_kernel, dim3(1), dim3(256), 0, stream,
                       x, wih, whh, bih, bhh, wfc, bfc, out);
}

// Round 2
// 46137.973 us; speedup vs baseline: 1.6939x; 1.6939x over previous
//
#include <hip/hip_runtime.h>
#include <stdint.h>
#include <stddef.h>

typedef _Float16 h2 __attribute__((ext_vector_type(2)));

#define T_STEPS 32768
#define HDIM    256

__device__ __forceinline__ float sigmoidf_(float x) {
    return 1.0f / (1.0f + __expf(-x));
}
__device__ __forceinline__ float tanhf_(float x) {
    float e2 = __expf(2.0f * x);
    return 1.0f - 2.0f / (e2 + 1.0f);
}

// One block, 512 threads = 8 waves (2/SIMD so all fit at <=256 VGPR — no spill).
// Thread (wave w, lane l): half hq = l>>5, result-row ri = w*32 + (l&31).
// Owns GRU rows {ri, 256+ri, 512+ri}, columns [hq*128, hq*128+128):
// 3 x 64 = 192 f16-pair weight registers. Half-sums combined with one
// shfl_down(32) per gate. h is f16 in double-buffered LDS (broadcast reads).
// x series staged entirely in LDS (128 KB) so the loop never reads global.
__global__ __launch_bounds__(512, 2)
void aether_gru_kernel(const float* __restrict__ xg,
                       const float* __restrict__ wih,
                       const float* __restrict__ whh,
                       const float* __restrict__ bih,
                       const float* __restrict__ bhh,
                       const float* __restrict__ wfc,
                       const float* __restrict__ bfc,
                       float* __restrict__ out) {
    const int tid  = threadIdx.x;
    const int lane = tid & 63;
    const int w    = tid >> 6;          // wave 0..7
    const int hq   = lane >> 5;         // column half 0/1
    const int ri   = w * 32 + (lane & 31);  // result row-group 0..255

    __shared__ float xlds[T_STEPS + 2];
    __shared__ __align__(16) _Float16 hbuf[2][HDIM];
    __shared__ float pp[2][8];

    // ---- stage x into LDS (coalesced float4) ----
    {
        const float4* xs4 = (const float4*)xg;
        float4* xd4 = (float4*)xlds;
        #pragma unroll
        for (int j = 0; j < T_STEPS / 4 / 512; ++j)
            xd4[tid + 512 * j] = xs4[tid + 512 * j];
        if (tid == 0) { xlds[T_STEPS] = 0.0f; xlds[T_STEPS + 1] = 0.0f; }
    }

    // ---- weights into registers: 3 gates x 64 f16-pairs ----
    h2 wr[64], wz[64], wn[64];
    {
        const float2* p = (const float2*)(whh + (size_t)ri * HDIM + hq * 128);
        #pragma unroll
        for (int k = 0; k < 64; ++k) {
            float2 v = p[k]; h2 q; q.x = (_Float16)v.x; q.y = (_Float16)v.y; wr[k] = q;
        }
    }
    {
        const float2* p = (const float2*)(whh + (size_t)(HDIM + ri) * HDIM + hq * 128);
        #pragma unroll
        for (int k = 0; k < 64; ++k) {
            float2 v = p[k]; h2 q; q.x = (_Float16)v.x; q.y = (_Float16)v.y; wz[k] = q;
        }
    }
    {
        const float2* p = (const float2*)(whh + (size_t)(2 * HDIM + ri) * HDIM + hq * 128);
        #pragma unroll
        for (int k = 0; k < 64; ++k) {
            float2 v = p[k]; h2 q; q.x = (_Float16)v.x; q.y = (_Float16)v.y; wn[k] = q;
        }
    }

    // per-result-row scalar constants (valid on low-half lanes; harmless elsewhere)
    const float wxr = wih[2 * ri],              wdr = wih[2 * ri + 1];
    const float wxz = wih[2 * (HDIM + ri)],     wdz = wih[2 * (HDIM + ri) + 1];
    const float wxn = wih[2 * (2 * HDIM + ri)], wdn = wih[2 * (2 * HDIM + ri) + 1];
    const float br = bih[ri], bz = bih[HDIM + ri], bn = bih[2 * HDIM + ri];
    // fold b_hh into the half that lane hq==0 accumulates? No: fold into both
    // halves would double it. Fold into accumulator only when hq==0.
    const float cr = (hq == 0) ? bhh[ri] : 0.0f;
    const float cz = (hq == 0) ? bhh[HDIM + ri] : 0.0f;
    const float cn = (hq == 0) ? bhh[2 * HDIM + ri] : 0.0f;
    const float wf = wfc[ri];
    const float bf = bfc[0];

    if (tid < HDIM) hbuf[0][tid] = (_Float16)0.0f;
    __syncthreads();

    // ---- sequential state (uniform across threads -> uniform branches) ----
    float hprev    = 0.0f;                  // this thread's row's h (f32)
    float last_val = xlds[0] + 1.24f;       // xs[0] + (2*THRESHOLD + 1.0)
    float last_t   = 0.0f;
    int   cnt      = 0;
    int   cur      = 0;                     // hbuf read index
    int   pe       = 0;                     // pp parity
    float cur_pred = 0.0f;

    float xc = xlds[0];
    float xn = xlds[1];

    float* recon = out;
    float* idxp  = out + T_STEPS + 1;

    for (int t = 0; t < T_STEPS; ++t) {
        float xf = xlds[t + 2];                      // LDS prefetch, 2 ahead
        const float tf = (float)t;
        const bool ev = fabsf(xc - last_val) >= 0.12f;

        if (ev) {
            const float dtv = (tf - last_t) * 0.01f;
            const float gir = fmaf(wxr, xc, fmaf(wdr, dtv, br));
            const float giz = fmaf(wxz, xc, fmaf(wdz, dtv, bz));
            const float gin = fmaf(wxn, xc, fmaf(wdn, dtv, bn));

            float ar = cr, az = cz, an = cn;
            const uint4* hb = (const uint4*)(&hbuf[cur][hq * 128]);
            #pragma unroll
            for (int c = 0; c < 16; ++c) {
                uint4 q = hb[c];                     // 8 f16, broadcast per half-wave
                h2 p0 = __builtin_bit_cast(h2, q.x);
                h2 p1 = __builtin_bit_cast(h2, q.y);
                h2 p2 = __builtin_bit_cast(h2, q.z);
                h2 p3 = __builtin_bit_cast(h2, q.w);
                const int k = c * 4;
                ar = __builtin_amdgcn_fdot2(wr[k + 0], p0, ar, false);
                az = __builtin_amdgcn_fdot2(wz[k + 0], p0, az, false);
                an = __builtin_amdgcn_fdot2(wn[k + 0], p0, an, false);
                ar = __builtin_amdgcn_fdot2(wr[k + 1], p1, ar, false);
                az = __builtin_amdgcn_fdot2(wz[k + 1], p1, az, false);
                an = __builtin_amdgcn_fdot2(wn[k + 1], p1, an, false);
                ar = __builtin_amdgcn_fdot2(wr[k + 2], p2, ar, false);
                az = __builtin_amdgcn_fdot2(wz[k + 2], p2, az, false);
                an = __builtin_amdgcn_fdot2(wn[k + 2], p2, an, false);
                ar = __builtin_amdgcn_fdot2(wr[k + 3], p3, ar, false);
                az = __builtin_amdgcn_fdot2(wz[k + 3], p3, az, false);
                an = __builtin_amdgcn_fdot2(wn[k + 3], p3, an, false);
            }
            // combine column-halves: low 32 lanes get full sums
            ar += __shfl_down(ar, 32);
            az += __shfl_down(az, 32);
            an += __shfl_down(an, 32);

            const float r = sigmoidf_(gir + ar);
            const float z = sigmoidf_(giz + az);
            const float n = tanhf_(fmaf(r, an, gin));
            const float hnew = fmaf(z, hprev, (1.0f - z) * n);
            hprev = hnew;                            // valid on low-half lanes

            if ((lane >> 5) == 0) hbuf[cur ^ 1][ri] = (_Float16)hnew;

            // fc partial: zero upper half, reduce 32 -> lane 0
            float pv = (lane < 32) ? hnew * wf : 0.0f;
            pv += __shfl_down(pv, 16);
            pv += __shfl_down(pv, 8);
            pv += __shfl_down(pv, 4);
            pv += __shfl_down(pv, 2);
            pv += __shfl_down(pv, 1);
            if (lane == 0) pp[pe][w] = pv;
            if (tid == 0) idxp[cnt] = tf;            // ascending -> sorted

            last_val = xc;
            last_t   = tf;
            cnt++;

            __syncthreads();                          // publish hbuf + pp
            cur ^= 1;
            if (tid == 0) {
                const float* q = &pp[pe][0];
                cur_pred = ((q[0] + q[1]) + (q[2] + q[3]))
                         + ((q[4] + q[5]) + (q[6] + q[7])) + bf;
            }
            pe ^= 1;
        }

        if (tid == 0) recon[t] = cur_pred;            // piecewise-constant pred
        xc = xn; xn = xf;
    }

    if (tid == 0) out[T_STEPS] = (float)cnt;          // n_events
    for (int j = cnt + tid; j < T_STEPS; j += 512)
        idxp[j] = 32768.0f;                           // pad with T
}

extern "C" void kernel_launch(void* const* d_in, const int* in_sizes, int n_in,
                              void* d_out, int out_size, void* d_ws, size_t ws_size,
                              hipStream_t stream) {
    const float* x    = (const float*)d_in[0];
    const float* wih  = (const float*)d_in[1];
    const float* whh  = (const float*)d_in[2];
    const float* bih  = (const float*)d_in[3];
    const float* bhh  = (const float*)d_in[4];
    const float* wfc  = (const float*)d_in[5];
    const float* bfc  = (const float*)d_in[6];
    float* out = (float*)d_out;

    hipLaunchKernelGGL(aether_gru_kernel, dim3(1), dim3(512), 0, stream,
                       x, wih, whh, bih, bhh, wfc, bfc, out);
}

// Round 3
// 43979.407 us; speedup vs baseline: 1.7770x; 1.0491x over previous
//
#include <hip/hip_runtime.h>
#include <stdint.h>
#include <stddef.h>

typedef _Float16 h2 __attribute__((ext_vector_type(2)));

#define T_STEPS 32768
#define HDIM    256

__device__ __forceinline__ float sigmoidf_(float x) {
    return 1.0f / (1.0f + __expf(-x));
}
__device__ __forceinline__ float tanhf_(float x) {
    float e2 = __expf(2.0f * x);
    return 1.0f - 2.0f / (e2 + 1.0f);
}

// One block, 512 threads = 8 waves = 2 waves/SIMD.
// amdgpu_waves_per_eu(2,2) pins the register budget to 512/2 = 256 VGPRs so
// the 192 weight-pair registers + temps stay resident (R2 spilled at the
// backend's default 4-wave/128-VGPR occupancy target).
// Thread (wave w, lane l): column-half hq = l>>5, result-row ri = w*32+(l&31).
// Owns GRU rows {ri, 256+ri, 512+ri}, columns [hq*128, hq*128+128):
// 3 x 64 f16-pair weight registers. Halves combined with one shfl_down(32).
// h is f16 in double-buffered LDS (broadcast reads); x staged in LDS (128 KB).
__global__
__attribute__((amdgpu_flat_work_group_size(512, 512), amdgpu_waves_per_eu(2, 2)))
void aether_gru_kernel(const float* __restrict__ xg,
                       const float* __restrict__ wih,
                       const float* __restrict__ whh,
                       const float* __restrict__ bih,
                       const float* __restrict__ bhh,
                       const float* __restrict__ wfc,
                       const float* __restrict__ bfc,
                       float* __restrict__ out) {
    const int tid  = threadIdx.x;
    const int lane = tid & 63;
    const int w    = tid >> 6;              // wave 0..7
    const int hq   = lane >> 5;             // column half 0/1
    const int ri   = w * 32 + (lane & 31);  // result row 0..255

    __shared__ float xlds[T_STEPS + 2];
    __shared__ __align__(16) _Float16 hbuf[2][HDIM];
    __shared__ float pp[2][8];

    // ---- stage x into LDS (coalesced float4) ----
    {
        const float4* xs4 = (const float4*)xg;
        float4* xd4 = (float4*)xlds;
        #pragma unroll
        for (int j = 0; j < T_STEPS / 4 / 512; ++j)
            xd4[tid + 512 * j] = xs4[tid + 512 * j];
        if (tid == 0) { xlds[T_STEPS] = 0.0f; xlds[T_STEPS + 1] = 0.0f; }
    }

    // ---- weights into registers: 3 gates x 64 f16-pairs ----
    h2 wr[64], wz[64], wn[64];
    {
        const float2* p = (const float2*)(whh + (size_t)ri * HDIM + hq * 128);
        #pragma unroll
        for (int k = 0; k < 64; ++k) {
            float2 v = p[k]; h2 q; q.x = (_Float16)v.x; q.y = (_Float16)v.y; wr[k] = q;
        }
    }
    {
        const float2* p = (const float2*)(whh + (size_t)(HDIM + ri) * HDIM + hq * 128);
        #pragma unroll
        for (int k = 0; k < 64; ++k) {
            float2 v = p[k]; h2 q; q.x = (_Float16)v.x; q.y = (_Float16)v.y; wz[k] = q;
        }
    }
    {
        const float2* p = (const float2*)(whh + (size_t)(2 * HDIM + ri) * HDIM + hq * 128);
        #pragma unroll
        for (int k = 0; k < 64; ++k) {
            float2 v = p[k]; h2 q; q.x = (_Float16)v.x; q.y = (_Float16)v.y; wn[k] = q;
        }
    }

    // per-result-row scalar constants
    const float wxr = wih[2 * ri],              wdr = wih[2 * ri + 1];
    const float wxz = wih[2 * (HDIM + ri)],     wdz = wih[2 * (HDIM + ri) + 1];
    const float wxn = wih[2 * (2 * HDIM + ri)], wdn = wih[2 * (2 * HDIM + ri) + 1];
    const float br = bih[ri], bz = bih[HDIM + ri], bn = bih[2 * HDIM + ri];
    // b_hh folded into the accumulator of column-half 0 only
    const float cr = (hq == 0) ? bhh[ri] : 0.0f;
    const float cz = (hq == 0) ? bhh[HDIM + ri] : 0.0f;
    const float cn = (hq == 0) ? bhh[2 * HDIM + ri] : 0.0f;
    const float wf = wfc[ri];
    const float bf = bfc[0];

    if (tid < HDIM) hbuf[0][tid] = (_Float16)0.0f;
    __syncthreads();

    // ---- sequential state (uniform across threads -> uniform branches) ----
    float hprev    = 0.0f;
    float last_val = xlds[0] + 1.24f;       // xs[0] + (2*THRESHOLD + 1.0)
    float last_t   = 0.0f;
    int   cnt      = 0;
    int   cur      = 0;                     // hbuf read index
    int   pe       = 0;                     // pp parity
    float cur_pred = 0.0f;

    float xc = xlds[0];
    float xn = xlds[1];

    float* recon = out;
    float* idxp  = out + T_STEPS + 1;

    for (int t = 0; t < T_STEPS; ++t) {
        float xf = xlds[t + 2];                      // LDS prefetch, 2 ahead
        const float tf = (float)t;
        const bool ev = fabsf(xc - last_val) >= 0.12f;

        if (ev) {
            const float dtv = (tf - last_t) * 0.01f;
            const float gir = fmaf(wxr, xc, fmaf(wdr, dtv, br));
            const float giz = fmaf(wxz, xc, fmaf(wdz, dtv, bz));
            const float gin = fmaf(wxn, xc, fmaf(wdn, dtv, bn));

            float ar = cr, az = cz, an = cn;
            const uint4* hb = (const uint4*)(&hbuf[cur][hq * 128]);
            #pragma unroll
            for (int c = 0; c < 16; ++c) {
                uint4 q = hb[c];                     // 8 f16, broadcast per half-wave
                h2 p0 = __builtin_bit_cast(h2, q.x);
                h2 p1 = __builtin_bit_cast(h2, q.y);
                h2 p2 = __builtin_bit_cast(h2, q.z);
                h2 p3 = __builtin_bit_cast(h2, q.w);
                const int k = c * 4;
                ar = __builtin_amdgcn_fdot2(wr[k + 0], p0, ar, false);
                az = __builtin_amdgcn_fdot2(wz[k + 0], p0, az, false);
                an = __builtin_amdgcn_fdot2(wn[k + 0], p0, an, false);
                ar = __builtin_amdgcn_fdot2(wr[k + 1], p1, ar, false);
                az = __builtin_amdgcn_fdot2(wz[k + 1], p1, az, false);
                an = __builtin_amdgcn_fdot2(wn[k + 1], p1, an, false);
                ar = __builtin_amdgcn_fdot2(wr[k + 2], p2, ar, false);
                az = __builtin_amdgcn_fdot2(wz[k + 2], p2, az, false);
                an = __builtin_amdgcn_fdot2(wn[k + 2], p2, an, false);
                ar = __builtin_amdgcn_fdot2(wr[k + 3], p3, ar, false);
                az = __builtin_amdgcn_fdot2(wz[k + 3], p3, az, false);
                an = __builtin_amdgcn_fdot2(wn[k + 3], p3, an, false);
            }
            // combine column-halves: low 32 lanes get full sums
            ar += __shfl_down(ar, 32);
            az += __shfl_down(az, 32);
            an += __shfl_down(an, 32);

            const float r = sigmoidf_(gir + ar);
            const float z = sigmoidf_(giz + az);
            const float n = tanhf_(fmaf(r, an, gin));
            const float hnew = fmaf(z, hprev, (1.0f - z) * n);
            hprev = hnew;                            // valid on low-half lanes

            if ((lane >> 5) == 0) hbuf[cur ^ 1][ri] = (_Float16)hnew;

            // fc partial: zero upper half, reduce 32 -> lane 0
            float pv = (lane < 32) ? hnew * wf : 0.0f;
            pv += __shfl_down(pv, 16);
            pv += __shfl_down(pv, 8);
            pv += __shfl_down(pv, 4);
            pv += __shfl_down(pv, 2);
            pv += __shfl_down(pv, 1);
            if (lane == 0) pp[pe][w] = pv;
            if (tid == 0) idxp[cnt] = tf;            // ascending -> sorted

            last_val = xc;
            last_t   = tf;
            cnt++;

            __syncthreads();                          // publish hbuf + pp
            cur ^= 1;
            if (tid == 0) {
                const float* q = &pp[pe][0];
                cur_pred = ((q[0] + q[1]) + (q[2] + q[3]))
                         + ((q[4] + q[5]) + (q[6] + q[7])) + bf;
            }
            pe ^= 1;
        }

        if (tid == 0) recon[t] = cur_pred;            // piecewise-constant pred
        xc = xn; xn = xf;
    }

    if (tid == 0) out[T_STEPS] = (float)cnt;          // n_events
    for (int j = cnt + tid; j < T_STEPS; j += 512)
        idxp[j] = 32768.0f;                           // pad with T
}

extern "C" void kernel_launch(void* const* d_in, const int* in_sizes, int n_in,
                              void* d_out, int out_size, void* d_ws, size_t ws_size,
                              hipStream_t stream) {
    const float* x    = (const float*)d_in[0];
    const float* wih  = (const float*)d_in[1];
    const float* whh  = (const float*)d_in[2];
    const float* bih  = (const float*)d_in[3];
    const float* bhh  = (const float*)d_in[4];
    const float* wfc  = (const float*)d_in[5];
    const float* bfc  = (const float*)d_in[6];
    float* out = (float*)d_out;

    hipLaunchKernelGGL(aether_gru_kernel, dim3(1), dim3(512), 0, stream,
                       x, wih, whh, bih, bhh, wfc, bfc, out);
}